// Round 20
// baseline (40.050 us; speedup 1.0000x reference)
//
#include <hip/hip_runtime.h>
#include <cstdint>

typedef unsigned short ushort_t;
typedef unsigned int u32;
typedef __attribute__((ext_vector_type(8))) short bf16x8;
typedef __attribute__((ext_vector_type(16))) float f32x16;

#define N_PRED 8192
#define N_GT   32768

// block = 4 waves sharing one 512-target split; wave = 128 preds x 512 targets
// NN: 16 pgBase x 64 splits = 1024 blocks; REP: 16 pgBase x 16 splits = 256
#define NN_BLOCKS 1024
#define RP_BLOCKS 256

// ws: chunkNN f32[64][8192] 2MB | chunkRP f32[16][8192] 512K | partials f32[2048][3]
#define O_CRP  2097152u
#define O_PART 2621440u

__device__ __forceinline__ float max3f(float a, float b, float c) {
    float d;
    asm("v_max3_f32 %0, %1, %2, %3" : "=v"(d) : "v"(a), "v"(b), "v"(c));
    return d;
}
__device__ __forceinline__ ushort_t f2b(float v) {   // round-to-nearest-even bf16
    u32 b = __float_as_uint(v);
    return (ushort_t)((b + 0x7FFFu + ((b >> 16) & 1u)) >> 16);
}
__device__ __forceinline__ float b2f(ushort_t h) {
    return __uint_as_float((u32)h << 16);
}
// final fold: 16-elem accumulator -> scalar (8 x v_max3 + 1 max3)
__device__ __forceinline__ float red16(const f32x16 a, float best) {
    const float m0 = max3f(a[0], a[1], a[2]);
    const float m1 = max3f(a[3], a[4], a[5]);
    const float m2 = max3f(a[6], a[7], a[8]);
    const float m3 = max3f(a[9], a[10], a[11]);
    const float m4 = max3f(a[12], a[13], a[14]);
    const float m5 = max3f(m0, m1, a[15]);
    const float m6 = max3f(m2, m3, m4);
    return max3f(best, m5, m6);
}

// mask the self element (C/D: col=lane&31, row=(r&3)+8*(r>>2)+4*(lane>>5))
#define MASKROW(ACC)                                               \
    {                                                              \
        _Pragma("unroll")                                          \
        for (int _r = 0; _r < 16; ++_r) {                          \
            const int _row = (_r & 3) + 8 * (_r >> 2) + rowoff;    \
            ACC[_r] = (_row == col) ? -3.0e38f : ACC[_r];          \
        }                                                          \
    }

// process one tile-pair for one B: 2 MFMA + 16 dependency-free max3
#define STEP2(ACC, BF, TS)                                                     \
    {                                                                          \
        f32x16 _d0 = __builtin_amdgcn_mfma_f32_32x32x16_bf16(Af0, BF, zc, 0, 0, 0); \
        f32x16 _d1 = __builtin_amdgcn_mfma_f32_32x32x16_bf16(Af1, BF, zc, 0, 0, 0); \
        if (DIAG && t0 == (TS)) MASKROW(_d0);                                  \
        if (DIAG && t0 + 1 == (TS)) MASKROW(_d1);                              \
        _Pragma("unroll")                                                      \
        for (int _i = 0; _i < 16; ++_i)                                        \
            ACC[_i] = max3f(ACC[_i], _d0[_i], _d1[_i]);                        \
    }

// ---- scan: 16 A-tiles from LDS, elementwise-accumulated per-split max ----
template <bool DIAG>
__device__ __forceinline__ void scan16(const bf16x8* __restrict__ ap,
                                       const bf16x8 B0, const bf16x8 B1,
                                       const bf16x8 B2, const bf16x8 B3,
                                       const int ts0, const int ts1,
                                       const int ts2, const int ts3,
                                       const int col, const int rowoff,
                                       float& b0, float& b1, float& b2, float& b3) {
    const f32x16 zc = {};
    f32x16 a0, a1, a2, a3;
#pragma unroll
    for (int i = 0; i < 16; ++i) {
        a0[i] = -3.0e38f; a1[i] = -3.0e38f; a2[i] = -3.0e38f; a3[i] = -3.0e38f;
    }
    bf16x8 Af0 = ap[0];
    bf16x8 Af1 = ap[64];
#pragma unroll
    for (int tp = 0; tp < 8; ++tp) {
        const int t0 = tp * 2;
        const bf16x8 An0 = (tp < 7) ? ap[(t0 + 2) * 64] : Af0;
        const bf16x8 An1 = (tp < 7) ? ap[(t0 + 3) * 64] : Af1;
        STEP2(a0, B0, ts0);
        STEP2(a1, B1, ts1);
        STEP2(a2, B2, ts2);
        STEP2(a3, B3, ts3);
        Af0 = An0;
        Af1 = An1;
    }
    b0 = red16(a0, b0);
    b1 = red16(a1, b1);
    b2 = red16(a2, b2);
    b3 = red16(a3, b3);
}

// ---- fused pair: in-kernel fragment pack (A->LDS, B->regs) + MFMA max ----
// A (target): k0-7=[xh,yh,zh,xh,yh,zh,xl,yl]  k8-15=[zl,wh,wl,0...]  (w=-0.5|g|^2)
// B (query) : k0-7=[xh,yh,zh,xl,yl,zl,xh,yh]  k8-15=[zh,1,1,0...]
__global__ __launch_bounds__(256) void k_pair(const float* __restrict__ pred,
                                              const float* __restrict__ gt,
                                              float* __restrict__ chunkNN,
                                              float* __restrict__ chunkRP) {
    __shared__ bf16x8 As[1024];          // 16 tiles x 64 frags = 16 KB
    const int w = threadIdx.x >> 6;
    const int lane = threadIdx.x & 63;
    const int b = blockIdx.x;
    const bool isNN = (b < NN_BLOCKS);
    const int pgBase = isNN ? (b >> 6) : ((b - NN_BLOCKS) >> 4);
    const int sp     = isNN ? (b & 63) : ((b - NN_BLOCKS) & 15);
    const int pg = pgBase * 4 + w;

    // ---- stage the 512-target split into LDS (2 points/thread) ----
    const float* __restrict__ src = isNN ? gt : pred;
#pragma unroll
    for (int k = 0; k < 2; ++k) {
        const int idx = k * 256 + threadIdx.x;      // 0..511
        const int gidx = sp * 512 + idx;
        const float x = src[gidx * 6 + 0], y = src[gidx * 6 + 1], z = src[gidx * 6 + 2];
        const ushort_t xh = f2b(x), yh = f2b(y), zh = f2b(z);
        const ushort_t xl = f2b(x - b2f(xh));
        const ushort_t yl = f2b(y - b2f(yh));
        const ushort_t zl = f2b(z - b2f(zh));
        const float wv = -0.5f * fmaf(z, z, fmaf(y, y, x * x));
        const ushort_t wh = f2b(wv);
        const ushort_t wl = f2b(wv - b2f(wh));
        bf16x8 h0, h1;
        h0[0] = (short)xh; h0[1] = (short)yh; h0[2] = (short)zh; h0[3] = (short)xh;
        h0[4] = (short)yh; h0[5] = (short)zh; h0[6] = (short)xl; h0[7] = (short)yl;
        h1[0] = (short)zl; h1[1] = (short)wh; h1[2] = (short)wl; h1[3] = 0;
        h1[4] = 0; h1[5] = 0; h1[6] = 0; h1[7] = 0;
        const int t = idx >> 5, row_ = idx & 31;
        As[t * 64 + row_] = h0;
        As[t * 64 + 32 + row_] = h1;
    }

    // ---- B fragments from raw pred (4 per lane) ----
    const int col = lane & 31;
    const int kh = lane >> 5;
    const int rowoff = kh * 4;
    const ushort_t ONE = 0x3F80;
    bf16x8 B[4];
#pragma unroll
    for (int j = 0; j < 4; ++j) {
        const int p = pg * 128 + j * 32 + col;
        const float x = pred[p * 6 + 0], y = pred[p * 6 + 1], z = pred[p * 6 + 2];
        const ushort_t xh = f2b(x), yh = f2b(y), zh = f2b(z);
        const ushort_t xl = f2b(x - b2f(xh));
        const ushort_t yl = f2b(y - b2f(yh));
        const ushort_t zl = f2b(z - b2f(zh));
        B[j][0] = (short)(kh ? zh : xh);
        B[j][1] = (short)(kh ? ONE : yh);
        B[j][2] = (short)(kh ? ONE : zh);
        B[j][3] = (short)(kh ? 0 : xl);
        B[j][4] = (short)(kh ? 0 : yl);
        B[j][5] = (short)(kh ? 0 : zl);
        B[j][6] = (short)(kh ? 0 : xh);
        B[j][7] = (short)(kh ? 0 : yh);
    }
    __syncthreads();

    const bf16x8* ap = &As[lane];
    float b0 = -3.0e38f, b1 = -3.0e38f, b2 = -3.0e38f, b3 = -3.0e38f;

    const bool diag = (!isNN) && (sp == pgBase);    // block-uniform
    if (diag) {
        const int tb = w * 4;                        // self tiles for j=0..3
        scan16<true>(ap, B[0], B[1], B[2], B[3], tb, tb + 1, tb + 2, tb + 3,
                     col, rowoff, b0, b1, b2, b3);
    } else {
        scan16<false>(ap, B[0], B[1], B[2], B[3], -1, -1, -1, -1,
                      col, rowoff, b0, b1, b2, b3);
    }

    // merge row-halves (lane, lane^32 share a pred col)
    b0 = fmaxf(b0, __shfl_xor(b0, 32));
    b1 = fmaxf(b1, __shfl_xor(b1, 32));
    b2 = fmaxf(b2, __shfl_xor(b2, 32));
    b3 = fmaxf(b3, __shfl_xor(b3, 32));

    if (lane < 32) {
        float* chunk = isNN ? chunkNN : chunkRP;
        const int base = sp * N_PRED + pg * 128 + col;
        chunk[base +  0] = b0;
        chunk[base + 32] = b1;
        chunk[base + 64] = b2;
        chunk[base + 96] = b3;
    }
}

// ---- finalize: wave-per-pred; split reduce; 512-point exact rescans; losses ----
__global__ __launch_bounds__(256) void k_fin(const float* __restrict__ pred,
                                             const float* __restrict__ gt,
                                             const float* __restrict__ chunkNN,
                                             const float* __restrict__ chunkRP,
                                             float* __restrict__ partials) {
    const int wave = threadIdx.x >> 6;
    const int lane = threadIdx.x & 63;
    const int p = blockIdx.x * 4 + wave;

    const float px = pred[p * 6 + 0], py = pred[p * 6 + 1], pz = pred[p * 6 + 2];

    // --- NN: argmax split over 64 approx maxes (tie -> smaller split) ---
    float m = chunkNN[lane * N_PRED + p];
    int c = lane;
#pragma unroll
    for (int off = 32; off > 0; off >>= 1) {
        const float om = __shfl_xor(m, off);
        const int   oc = __shfl_xor(c, off);
        const bool take = (om > m) || (om == m && oc < c);
        m = take ? om : m;
        c = take ? oc : c;
    }
    // exact fp32 rescan of 512-gt split (ascending g; ties -> smallest index)
    float bh = -3.0e38f;
    int bj = 0x7FFFFFFF;
#pragma unroll 2
    for (int i = 0; i < 8; ++i) {
        const int g = c * 512 + i * 64 + lane;
        const float x = gt[g * 6 + 0], y = gt[g * 6 + 1], z = gt[g * 6 + 2];
        const float w = -0.5f * fmaf(z, z, fmaf(y, y, x * x));
        const float h = fmaf(px, x, fmaf(py, y, fmaf(pz, z, w)));
        if (h > bh) { bh = h; bj = g; }
    }
#pragma unroll
    for (int off = 32; off > 0; off >>= 1) {
        const float oh = __shfl_xor(bh, off);
        const int og = __shfl_xor(bj, off);
        const bool take = (oh > bh) || (oh == bh && og < bj);
        bh = take ? oh : bh;
        bj = take ? og : bj;
    }
    const int j = bj;

    // --- REP: argmax split over 16 self-free maxes, exact rescan (value only) ---
    float rm = (lane < 16) ? chunkRP[lane * N_PRED + p] : -3.0e38f;
    int rc = (lane < 16) ? lane : 0;
#pragma unroll
    for (int off = 32; off > 0; off >>= 1) {
        const float om = __shfl_xor(rm, off);
        const int   oc = __shfl_xor(rc, off);
        const bool take = (om > rm) || (om == rm && oc < rc);
        rm = take ? om : rm;
        rc = take ? oc : rc;
    }
    float hr = -3.0e38f;
#pragma unroll 2
    for (int i = 0; i < 8; ++i) {
        const int q = rc * 512 + i * 64 + lane;
        const float x = pred[q * 6 + 0], y = pred[q * 6 + 1], z = pred[q * 6 + 2];
        const float w = -0.5f * fmaf(z, z, fmaf(y, y, x * x));
        float h = fmaf(px, x, fmaf(py, y, fmaf(pz, z, w)));
        h = (q == p) ? -3.0e38f : h;
        hr = fmaxf(hr, h);
    }
#pragma unroll
    for (int off = 32; off > 0; off >>= 1) hr = fmaxf(hr, __shfl_xor(hr, off));

    __shared__ float red[4][3];
    if (lane == 0) {
        const float gx = gt[j * 6 + 0], gy = gt[j * 6 + 1], gz = gt[j * 6 + 2];
        const float dx = px - gx, dy = py - gy, dz = pz - gz;
        const float att = dx * dx + dy * dy + dz * dz;

        const float pnx = pred[p * 6 + 3], pny = pred[p * 6 + 4], pnz = pred[p * 6 + 5];
        const float gnx = gt[j * 6 + 3],   gny = gt[j * 6 + 4],   gnz = gt[j * 6 + 5];
        const float pl = fmaxf(sqrtf(pnx * pnx + pny * pny + pnz * pnz), 1e-5f);
        const float gl = fmaxf(sqrtf(gnx * gnx + gny * gny + gnz * gnz), 1e-5f);
        const float nrm = 1.0f - (pnx * gnx + pny * gny + pnz * gnz) / (pl * gl);

        const float pp2 = px * px + py * py + pz * pz;
        float d2 = fmaf(-2.0f, hr, pp2);
        d2 = fmaxf(d2, 0.0f);
        const float xa = 100.0f * (0.3f - sqrtf(d2));
        const float sp2 = fmaxf(xa, 0.0f) + log1pf(expf(-fabsf(xa)));

        red[wave][0] = att;
        red[wave][1] = nrm;
        red[wave][2] = sp2 * sp2;
    }
    __syncthreads();
    if (threadIdx.x < 3)
        partials[blockIdx.x * 3 + threadIdx.x] =
            red[0][threadIdx.x] + red[1][threadIdx.x] +
            red[2][threadIdx.x] + red[3][threadIdx.x];
}

__device__ __forceinline__ float wave_reduce(float v) {
#pragma unroll
    for (int off = 32; off > 0; off >>= 1) v += __shfl_down(v, off, 64);
    return v;
}

__global__ __launch_bounds__(256) void k_comb(const float* __restrict__ partials,
                                              float* __restrict__ out) {
    float a = 0.f, n = 0.f, r = 0.f;
    const int t = threadIdx.x;
#pragma unroll
    for (int k = 0; k < 8; ++k) {
        const int row = t + k * 256;          // 2048 rows
        a += partials[row * 3 + 0];
        n += partials[row * 3 + 1];
        r += partials[row * 3 + 2];
    }
    a = wave_reduce(a);
    n = wave_reduce(n);
    r = wave_reduce(r);
    __shared__ float red[3][4];
    const int wave = t >> 6, lane = t & 63;
    if (lane == 0) { red[0][wave] = a; red[1][wave] = n; red[2][wave] = r; }
    __syncthreads();
    if (t == 0) {
        const float A = red[0][0] + red[0][1] + red[0][2] + red[0][3];
        const float Nn = red[1][0] + red[1][1] + red[1][2] + red[1][3];
        const float R = red[2][0] + red[2][1] + red[2][2] + red[2][3];
        out[0] = A / (float)(N_PRED * 3) + R / (float)N_PRED + 10.0f * (Nn / (float)N_PRED);
    }
}

extern "C" void kernel_launch(void* const* d_in, const int* in_sizes, int n_in,
                              void* d_out, int out_size, void* d_ws, size_t ws_size,
                              hipStream_t stream) {
    const float* pred = (const float*)d_in[0];   // (8192, 6)
    const float* gt   = (const float*)d_in[3];   // (32768, 6)
    float* out = (float*)d_out;
    char* ws = (char*)d_ws;

    float* chunkNN = (float*)ws;
    float* chunkRP = (float*)(ws + O_CRP);
    float* partials = (float*)(ws + O_PART);

    k_pair<<<NN_BLOCKS + RP_BLOCKS, 256, 0, stream>>>(pred, gt, chunkNN, chunkRP);
    k_fin<<<N_PRED / 4, 256, 0, stream>>>(pred, gt, chunkNN, chunkRP, partials);
    k_comb<<<1, 256, 0, stream>>>(partials, out);
}

// Round 21
// 35.416 us; speedup vs baseline: 1.1308x; 1.1308x over previous
//
#include <hip/hip_runtime.h>
#include <cstdint>

typedef unsigned short ushort_t;
typedef unsigned int u32;
typedef unsigned long long u64;
typedef __attribute__((ext_vector_type(8))) short bf16x8;
typedef __attribute__((ext_vector_type(16))) float f32x16;

#define N_PRED 8192
#define N_GT   32768

// block = 4 waves sharing one 512-target split; wave = 128 preds x 512 targets
// NN: 16 pgBase x 64 splits = 1024 blocks; REP: 16 pgBase x 16 splits = 256
#define NN_BLOCKS 1024
#define RP_BLOCKS 256

// ws: keysNN u64[64][8192] 4MB | keysRP u64[16][8192] 1MB | partials f32[2048][3]
#define O_KRP  4194304u
#define O_PART 5242880u

__device__ __forceinline__ float max3f(float a, float b, float c) {
    float d;
    asm("v_max3_f32 %0, %1, %2, %3" : "=v"(d) : "v"(a), "v"(b), "v"(c));
    return d;
}
__device__ __forceinline__ ushort_t f2b(float v) {   // round-to-nearest-even bf16
    u32 b = __float_as_uint(v);
    return (ushort_t)((b + 0x7FFFu + ((b >> 16) & 1u)) >> 16);
}
__device__ __forceinline__ float b2f(ushort_t h) {
    return __uint_as_float((u32)h << 16);
}
__device__ __forceinline__ u32 packf(float v) {      // monotone float->u32
    const u32 b = __float_as_uint(v);
    return b ^ ((u32)((int)b >> 31) | 0x80000000u);
}
// fold 16 accs into running max (8 x v_max3 + 1 fmax)
__device__ __forceinline__ float red16(const f32x16 a, float best) {
    const float m0 = max3f(a[0], a[1], a[2]);
    const float m1 = max3f(a[3], a[4], a[5]);
    const float m2 = max3f(a[6], a[7], a[8]);
    const float m3 = max3f(a[9], a[10], a[11]);
    const float m4 = max3f(a[12], a[13], a[14]);
    const float m5 = max3f(m0, m1, a[15]);
    const float m6 = max3f(m2, m3, m4);
    return max3f(best, m5, m6);
}

// mask the self element (C/D: col=lane&31, row=(r&3)+8*(r>>2)+4*(lane>>5))
#define MASKROW(ACC)                                               \
    {                                                              \
        _Pragma("unroll")                                          \
        for (int _r = 0; _r < 16; ++_r) {                          \
            const int _row = (_r & 3) + 8 * (_r >> 2) + rowoff;    \
            ACC[_r] = (_row == col) ? -3.0e38f : ACC[_r];          \
        }                                                          \
    }

// ---- scan: 16 A-tiles from LDS, lean body, argmax latched per 4-tile group ----
template <bool DIAG>
__device__ __forceinline__ void scan16(const bf16x8* __restrict__ ap,
                                       const bf16x8 B0, const bf16x8 B1,
                                       const bf16x8 B2, const bf16x8 B3,
                                       const int ts0, const int ts1,
                                       const int ts2, const int ts3,
                                       const int col, const int rowoff,
                                       float& b0, float& b1, float& b2, float& b3,
                                       u32& k0, u32& k1, u32& k2, u32& k3) {
    const f32x16 zc = {};
    bf16x8 Acur = ap[0];
#pragma unroll
    for (int G = 0; G < 4; ++G) {
        float g0 = -3.0e38f, g1 = -3.0e38f, g2 = -3.0e38f, g3 = -3.0e38f;
#pragma unroll
        for (int tt = 0; tt < 4; ++tt) {
            const int t = G * 4 + tt;
            const bf16x8 Anxt = (t < 15) ? ap[(t + 1) * 64] : Acur;
            f32x16 accA = __builtin_amdgcn_mfma_f32_32x32x16_bf16(Acur, B0, zc, 0, 0, 0);
            f32x16 accB = __builtin_amdgcn_mfma_f32_32x32x16_bf16(Acur, B1, zc, 0, 0, 0);
            if (DIAG && t == ts0) MASKROW(accA);
            g0 = red16(accA, g0);
            accA = __builtin_amdgcn_mfma_f32_32x32x16_bf16(Acur, B2, zc, 0, 0, 0);
            if (DIAG && t == ts1) MASKROW(accB);
            g1 = red16(accB, g1);
            accB = __builtin_amdgcn_mfma_f32_32x32x16_bf16(Acur, B3, zc, 0, 0, 0);
            if (DIAG && t == ts2) MASKROW(accA);
            g2 = red16(accA, g2);
            if (DIAG && t == ts3) MASKROW(accB);
            g3 = red16(accB, g3);
            Acur = Anxt;
        }
        k0 = (g0 > b0) ? (u32)G : k0;  b0 = fmaxf(b0, g0);
        k1 = (g1 > b1) ? (u32)G : k1;  b1 = fmaxf(b1, g1);
        k2 = (g2 > b2) ? (u32)G : k2;  b2 = fmaxf(b2, g2);
        k3 = (g3 > b3) ? (u32)G : k3;  b3 = fmaxf(b3, g3);
    }
}

// ---- fused pair: in-kernel fragment pack (A->LDS, B->regs) + MFMA argmax ----
// A (target): k0-7=[xh,yh,zh,xh,yh,zh,xl,yl]  k8-15=[zl,wh,wl,0...]  (w=-0.5|g|^2)
// B (query) : k0-7=[xh,yh,zh,xl,yl,zl,xh,yh]  k8-15=[zh,1,1,0...]
__global__ __launch_bounds__(256) void k_pair(const float* __restrict__ pred,
                                              const float* __restrict__ gt,
                                              u64* __restrict__ keysNN,
                                              u64* __restrict__ keysRP) {
    __shared__ bf16x8 As[1024];          // 16 tiles x 64 frags = 16 KB
    const int w = threadIdx.x >> 6;
    const int lane = threadIdx.x & 63;
    const int b = blockIdx.x;
    const bool isNN = (b < NN_BLOCKS);
    const int pgBase = isNN ? (b >> 6) : ((b - NN_BLOCKS) >> 4);
    const int sp     = isNN ? (b & 63) : ((b - NN_BLOCKS) & 15);
    const int pg = pgBase * 4 + w;

    // ---- stage the 512-target split into LDS (2 points/thread) ----
    const float* __restrict__ src = isNN ? gt : pred;
#pragma unroll
    for (int k = 0; k < 2; ++k) {
        const int idx = k * 256 + threadIdx.x;      // 0..511
        const int gidx = sp * 512 + idx;
        const float x = src[gidx * 6 + 0], y = src[gidx * 6 + 1], z = src[gidx * 6 + 2];
        const ushort_t xh = f2b(x), yh = f2b(y), zh = f2b(z);
        const ushort_t xl = f2b(x - b2f(xh));
        const ushort_t yl = f2b(y - b2f(yh));
        const ushort_t zl = f2b(z - b2f(zh));
        const float wv = -0.5f * fmaf(z, z, fmaf(y, y, x * x));
        const ushort_t wh = f2b(wv);
        const ushort_t wl = f2b(wv - b2f(wh));
        bf16x8 h0, h1;
        h0[0] = (short)xh; h0[1] = (short)yh; h0[2] = (short)zh; h0[3] = (short)xh;
        h0[4] = (short)yh; h0[5] = (short)zh; h0[6] = (short)xl; h0[7] = (short)yl;
        h1[0] = (short)zl; h1[1] = (short)wh; h1[2] = (short)wl; h1[3] = 0;
        h1[4] = 0; h1[5] = 0; h1[6] = 0; h1[7] = 0;
        const int t = idx >> 5, row_ = idx & 31;
        As[t * 64 + row_] = h0;
        As[t * 64 + 32 + row_] = h1;
    }

    // ---- B fragments from raw pred (4 per lane) ----
    const int col = lane & 31;
    const int kh = lane >> 5;
    const int rowoff = kh * 4;
    const ushort_t ONE = 0x3F80;
    bf16x8 B[4];
#pragma unroll
    for (int j = 0; j < 4; ++j) {
        const int p = pg * 128 + j * 32 + col;
        const float x = pred[p * 6 + 0], y = pred[p * 6 + 1], z = pred[p * 6 + 2];
        const ushort_t xh = f2b(x), yh = f2b(y), zh = f2b(z);
        const ushort_t xl = f2b(x - b2f(xh));
        const ushort_t yl = f2b(y - b2f(yh));
        const ushort_t zl = f2b(z - b2f(zh));
        B[j][0] = (short)(kh ? zh : xh);
        B[j][1] = (short)(kh ? ONE : yh);
        B[j][2] = (short)(kh ? ONE : zh);
        B[j][3] = (short)(kh ? 0 : xl);
        B[j][4] = (short)(kh ? 0 : yl);
        B[j][5] = (short)(kh ? 0 : zl);
        B[j][6] = (short)(kh ? 0 : xh);
        B[j][7] = (short)(kh ? 0 : yh);
    }
    __syncthreads();

    const bf16x8* ap = &As[lane];
    float b0 = -3.0e38f, b1 = -3.0e38f, b2 = -3.0e38f, b3 = -3.0e38f;
    u32 k0 = 0, k1 = 0, k2 = 0, k3 = 0;

    const bool diag = (!isNN) && (sp == pgBase);    // block-uniform
    if (diag) {
        const int tb = w * 4;                        // self tiles for j=0..3
        scan16<true>(ap, B[0], B[1], B[2], B[3], tb, tb + 1, tb + 2, tb + 3,
                     col, rowoff, b0, b1, b2, b3, k0, k1, k2, k3);
    } else {
        scan16<false>(ap, B[0], B[1], B[2], B[3], -1, -1, -1, -1,
                      col, rowoff, b0, b1, b2, b3, k0, k1, k2, k3);
    }

    // merge row-halves (lane, lane^32 share a pred col); tie -> smaller group
#define FOLD(B_, K_)                                                \
    {                                                               \
        const float _ob = __shfl_xor(B_, 32);                       \
        const u32 _ok = __shfl_xor(K_, 32);                         \
        const bool _tk = (_ob > B_) || (_ob == B_ && _ok < K_);     \
        B_ = _tk ? _ob : B_;                                        \
        K_ = _tk ? _ok : K_;                                        \
    }
    FOLD(b0, k0); FOLD(b1, k1); FOLD(b2, k2); FOLD(b3, k3);
#undef FOLD

    if (lane < 32) {
        u64* keys = isNN ? keysNN : keysRP;
        const int Pb = pg * 128 + col;
        const u32 gb = (u32)(sp * 4);
        keys[(size_t)sp * N_PRED + Pb +  0] = ((u64)packf(b0) << 32) | (u64)(~(gb + k0));
        keys[(size_t)sp * N_PRED + Pb + 32] = ((u64)packf(b1) << 32) | (u64)(~(gb + k1));
        keys[(size_t)sp * N_PRED + Pb + 64] = ((u64)packf(b2) << 32) | (u64)(~(gb + k2));
        keys[(size_t)sp * N_PRED + Pb + 96] = ((u64)packf(b3) << 32) | (u64)(~(gb + k3));
    }
}

// ---- finalize: wave-per-pred; key reduce; 128-point exact rescans; losses ----
__global__ __launch_bounds__(256) void k_fin(const float* __restrict__ pred,
                                             const float* __restrict__ gt,
                                             const u64* __restrict__ keysNN,
                                             const u64* __restrict__ keysRP,
                                             float* __restrict__ partials) {
    const int wave = threadIdx.x >> 6;
    const int lane = threadIdx.x & 63;
    const int p = blockIdx.x * 4 + wave;

    const float px = pred[p * 6 + 0], py = pred[p * 6 + 1], pz = pred[p * 6 + 2];

    // --- NN: reduce 64 split keys (bigger h, then smaller group) ---
    u64 kv = keysNN[(size_t)lane * N_PRED + p];
#pragma unroll
    for (int off = 32; off > 0; off >>= 1) {
        const u64 o = __shfl_xor(kv, off);
        kv = (o > kv) ? o : kv;
    }
    const int G = (int)(~(u32)kv);          // group of 128 gt
    // exact fp32 rescan (ascending i -> numpy first-max tie semantics)
    float bh = -3.0e38f;
    int bj = 0x7FFFFFFF;
#pragma unroll
    for (int i = 0; i < 2; ++i) {
        const int g = G * 128 + i * 64 + lane;
        const float x = gt[g * 6 + 0], y = gt[g * 6 + 1], z = gt[g * 6 + 2];
        const float w = -0.5f * fmaf(z, z, fmaf(y, y, x * x));
        const float h = fmaf(px, x, fmaf(py, y, fmaf(pz, z, w)));
        if (h > bh) { bh = h; bj = g; }
    }
#pragma unroll
    for (int off = 32; off > 0; off >>= 1) {
        const float oh = __shfl_xor(bh, off);
        const int og = __shfl_xor(bj, off);
        const bool take = (oh > bh) || (oh == bh && og < bj);
        bh = take ? oh : bh;
        bj = take ? og : bj;
    }
    const int j = bj;

    // --- REP: reduce 16 self-free split keys, exact 128-point rescan ---
    u64 rv = (lane < 16) ? keysRP[(size_t)lane * N_PRED + p] : 0ull;
#pragma unroll
    for (int off = 32; off > 0; off >>= 1) {
        const u64 o = __shfl_xor(rv, off);
        rv = (o > rv) ? o : rv;
    }
    const int G2 = (int)(~(u32)rv);         // group of 128 pred
    float hr = -3.0e38f;
#pragma unroll
    for (int i = 0; i < 2; ++i) {
        const int q = G2 * 128 + i * 64 + lane;
        const float x = pred[q * 6 + 0], y = pred[q * 6 + 1], z = pred[q * 6 + 2];
        const float w = -0.5f * fmaf(z, z, fmaf(y, y, x * x));
        float h = fmaf(px, x, fmaf(py, y, fmaf(pz, z, w)));
        h = (q == p) ? -3.0e38f : h;
        hr = fmaxf(hr, h);
    }
#pragma unroll
    for (int off = 32; off > 0; off >>= 1) hr = fmaxf(hr, __shfl_xor(hr, off));

    __shared__ float red[4][3];
    if (lane == 0) {
        const float gx = gt[j * 6 + 0], gy = gt[j * 6 + 1], gz = gt[j * 6 + 2];
        const float dx = px - gx, dy = py - gy, dz = pz - gz;
        const float att = dx * dx + dy * dy + dz * dz;

        const float pnx = pred[p * 6 + 3], pny = pred[p * 6 + 4], pnz = pred[p * 6 + 5];
        const float gnx = gt[j * 6 + 3],   gny = gt[j * 6 + 4],   gnz = gt[j * 6 + 5];
        const float pl = fmaxf(sqrtf(pnx * pnx + pny * pny + pnz * pnz), 1e-5f);
        const float gl = fmaxf(sqrtf(gnx * gnx + gny * gny + gnz * gnz), 1e-5f);
        const float nrm = 1.0f - (pnx * gnx + pny * gny + pnz * gnz) / (pl * gl);

        const float pp2 = px * px + py * py + pz * pz;
        float d2 = fmaf(-2.0f, hr, pp2);
        d2 = fmaxf(d2, 0.0f);
        const float xa = 100.0f * (0.3f - sqrtf(d2));
        const float sp2 = fmaxf(xa, 0.0f) + log1pf(expf(-fabsf(xa)));

        red[wave][0] = att;
        red[wave][1] = nrm;
        red[wave][2] = sp2 * sp2;
    }
    __syncthreads();
    if (threadIdx.x < 3)
        partials[blockIdx.x * 3 + threadIdx.x] =
            red[0][threadIdx.x] + red[1][threadIdx.x] +
            red[2][threadIdx.x] + red[3][threadIdx.x];
}

__device__ __forceinline__ float wave_reduce(float v) {
#pragma unroll
    for (int off = 32; off > 0; off >>= 1) v += __shfl_down(v, off, 64);
    return v;
}

__global__ __launch_bounds__(256) void k_comb(const float* __restrict__ partials,
                                              float* __restrict__ out) {
    float a = 0.f, n = 0.f, r = 0.f;
    const int t = threadIdx.x;
#pragma unroll
    for (int k = 0; k < 8; ++k) {
        const int row = t + k * 256;          // 2048 rows
        a += partials[row * 3 + 0];
        n += partials[row * 3 + 1];
        r += partials[row * 3 + 2];
    }
    a = wave_reduce(a);
    n = wave_reduce(n);
    r = wave_reduce(r);
    __shared__ float red[3][4];
    const int wave = t >> 6, lane = t & 63;
    if (lane == 0) { red[0][wave] = a; red[1][wave] = n; red[2][wave] = r; }
    __syncthreads();
    if (t == 0) {
        const float A = red[0][0] + red[0][1] + red[0][2] + red[0][3];
        const float Nn = red[1][0] + red[1][1] + red[1][2] + red[1][3];
        const float R = red[2][0] + red[2][1] + red[2][2] + red[2][3];
        out[0] = A / (float)(N_PRED * 3) + R / (float)N_PRED + 10.0f * (Nn / (float)N_PRED);
    }
}

extern "C" void kernel_launch(void* const* d_in, const int* in_sizes, int n_in,
                              void* d_out, int out_size, void* d_ws, size_t ws_size,
                              hipStream_t stream) {
    const float* pred = (const float*)d_in[0];   // (8192, 6)
    const float* gt   = (const float*)d_in[3];   // (32768, 6)
    float* out = (float*)d_out;
    char* ws = (char*)d_ws;

    u64* keysNN = (u64*)ws;
    u64* keysRP = (u64*)(ws + O_KRP);
    float* partials = (float*)(ws + O_PART);

    k_pair<<<NN_BLOCKS + RP_BLOCKS, 256, 0, stream>>>(pred, gt, keysNN, keysRP);
    k_fin<<<N_PRED / 4, 256, 0, stream>>>(pred, gt, keysNN, keysRP, partials);
    k_comb<<<1, 256, 0, stream>>>(partials, out);
}